// Round 17
// baseline (45.205 us; speedup 1.0000x reference)
//
#include <hip/hip_runtime.h>
#include <hip/hip_bf16.h>

// Hopf oscillator scan: B=32, T=1000, D=512.
// THREE-wave specialization; R16 change: 32 chains/block -> 512 blocks =
// 2 blocks/CU. R15 refuted per-round-overhead theory (U doubling was ~null);
// 4.4 TB/s vs 6.3 copy ceiling with only 1 loader+1 drainer wave per CU ->
// the untested lever is per-CU memory-level parallelism. 2 independent
// blocks/CU double outstanding loads/stores and decouple pacing.
//   wave 0 (consumer): all 64 lanes, d = lane&31 (upper half duplicates:
//     same LDS reads broadcast, same-value same-address OUT writes are
//     idempotent -> no divergence, no masking).
//   wave 1 (loader): global_load_lds dwordx4, 3-deep ring, 2 bodies ahead,
//     8 lanes/row (128B rows), steady wait vmcnt(10).
//   wave 2 (drainer): OUT[n-1] -> global (b128 LDS reads + nt x4 stores).
// LDS 51.2KB/block; __launch_bounds__(192,2) caps VGPR<=256 so 2 blocks/CU.

#define B 32
#define T 1000
#define D 512
#define NDB 32                    // d-chains per block
#define DTc 0.001f
#define K_IN 0.005f               // INPUT_SCALER * DT
#define KREV 7.95774715e-4f       // INPUT_SCALER * DT / (2*pi)
#define U 40                      // steps per body
#define NB (T / U)                // 25 bodies
#define NOPS 5                    // glds/drain ops per array per body (U*NDB*4B/1KB)
#define RING 3                    // IN ring depth

typedef float v4f __attribute__((ext_vector_type(4)));
typedef const __attribute__((address_space(1))) float gfloat;
typedef __attribute__((address_space(3))) float lfloat;

#define SCHEDB() __builtin_amdgcn_sched_barrier(0)
#define BAR()    __builtin_amdgcn_s_barrier()
// s_waitcnt simm16 (gfx9): [3:0]=vmcnt lo, [15:14]=vmcnt hi, [6:4]=expcnt, [11:8]=lgkmcnt
#define W_LGKM0  0xC07F   // lgkmcnt(0) only
#define W_VM0    0x0F70   // vmcnt(0)  only
#define W_VM10   0x0F7A   // vmcnt(10) only

__global__ __launch_bounds__(192, 2) void hopf_scan(
    const float* __restrict__ Xr, const float* __restrict__ Xi,
    const float* __restrict__ om,
    float* __restrict__ zr, float* __restrict__ zi) {
    const int tid = threadIdx.x;
    const int bb = blockIdx.x;            // 0..511
    const int b = bb >> 4;                // /16 dblk groups
    const int dblk = (bb & 15) << 5;      // 32-d block
    const size_t blkoff = (size_t)b * (T * D) + dblk;

    __shared__ __align__(16) float INr[RING][U][NDB];  // 3-deep input ring
    __shared__ __align__(16) float INi[RING][U][NDB];
    __shared__ __align__(16) float OUTr[2][U][NDB];    // double-buffered out
    __shared__ __align__(16) float OUTi[2][U][NDB];

    if (tid < 64) {
        // ---------------- wave 0: consumer (LDS + VALU only) ----------------
        const int i = tid & (NDB - 1);    // lanes 32-63 duplicate 0-31
        // rev/step: f_Hz * dt = (om*10 + 0.1) * dt
        const float od = __builtin_fmaf(om[dblk + i], 10.0f, 0.1f) * DTc;
        float r = 1.0f, phi = 0.0f, c = 1.0f, s = 0.0f;  // phi in revolutions

        BAR();                            // body 0 staged by loader
        int ib = 0;                       // ring slot of body n (mod 3)
        for (int n = 0; n < NB; ++n) {
            const int ob = n & 1;

            float xr[U], xi[U];
#pragma unroll
            for (int t = 0; t < U; ++t) {   // reg-burst: latency pipelines
                xr[t] = INr[ib][t][i];
                xi[t] = INi[ib][t][i];
            }
            SCHEDB();

            float our[U], oui[U];
#pragma unroll
            for (int t = 0; t < U; ++t) {
                const float omr2 = __builtin_fmaf(-r, r, 1.0f);   // 1 - r^2
                r = __builtin_fmaf(omr2 * r, DTc, r);             // + cubic*dt
                r = __builtin_fmaf(K_IN * xr[t], c, r);           // + K*xr*cos
                phi = __builtin_fmaf(-(KREV * xi[t]), s, phi + od);
                s = __builtin_amdgcn_sinf(phi);   // v_sin: input in revs
                c = __builtin_amdgcn_cosf(phi);
                our[t] = r * c;
                oui[t] = r * s;
            }
            SCHEDB();
#pragma unroll
            for (int t = 0; t < U; ++t) {
                OUTr[ob][t][i] = our[t];   // lanes i and i+32: same addr,
                OUTi[ob][t][i] = oui[t];   // same value -> idempotent
            }
            __builtin_amdgcn_s_waitcnt(W_LGKM0);  // OUT complete before BAR
            SCHEDB();
            BAR();
            ib = (ib == RING - 1) ? 0 : ib + 1;
        }
    } else if (tid < 128) {
        // ---------------- wave 1: loader (global->LDS only) -----------------
        const int i = tid - 64;
        const int ts = i >> 3;            // row 0..7 within a glds op
        const int dq = (i & 7) << 2;      // d quad within 32-d row
        const float* __restrict__ xr_blk = Xr + blkoff;
        const float* __restrict__ xi_blk = Xi + blkoff;

        auto issueglds = [&](int body, int buf) {
#pragma unroll
            for (int k = 0; k < NOPS; ++k) {
                const size_t off = (size_t)(body * U + 8 * k + ts) * D + dq;
                // LDS dest: uniform base + lane*16 == row 8k+ts, col dq
                // in the [U][32] row-major layout (128B rows).
                __builtin_amdgcn_global_load_lds((gfloat*)(xr_blk + off),
                                                 (lfloat*)&INr[buf][8 * k][0], 16, 0, 0);
                __builtin_amdgcn_global_load_lds((gfloat*)(xi_blk + off),
                                                 (lfloat*)&INi[buf][8 * k][0], 16, 0, 0);
            }
        };

        // prologue: bodies 0,1 in flight; body 0 landed when <=10 newer remain
        issueglds(0, 0);
        issueglds(1, 1);
        __builtin_amdgcn_s_waitcnt(W_VM10);
        SCHEDB();
        BAR();

        int bufn = 2;                     // ring slot for body n+2 (mod 3)
        for (int n = 0; n < NB; ++n) {
            if (n + 2 < NB) issueglds(n + 2, bufn);
            SCHEDB();
            if (n + 1 < NB) {
                // loads-only queue: newer than body n+1's are body n+2's
                // 10 ops (if issued).
                if (n + 2 < NB) __builtin_amdgcn_s_waitcnt(W_VM10);
                else            __builtin_amdgcn_s_waitcnt(W_VM0);
            }
            SCHEDB();
            BAR();
            bufn = (bufn == RING - 1) ? 0 : bufn + 1;
        }
    } else {
        // ---------------- wave 2: drainer (LDS->global only) ----------------
        const int i = tid - 128;
        const int ts = i >> 3;
        const int dq = (i & 7) << 2;
        float* __restrict__ zr_blk = zr + blkoff;
        float* __restrict__ zi_blk = zi + blkoff;

        auto drainbody = [&](int body) {
            const int ob = body & 1;
#pragma unroll
            for (int k = 0; k < NOPS; ++k) {
                const size_t off = (size_t)(body * U + 8 * k + ts) * D + dq;
                const v4f vr = *reinterpret_cast<const v4f*>(&OUTr[ob][8 * k + ts][dq]);
                const v4f vi = *reinterpret_cast<const v4f*>(&OUTi[ob][8 * k + ts][dq]);
                __builtin_nontemporal_store(vr, reinterpret_cast<v4f*>(zr_blk + off));
                __builtin_nontemporal_store(vi, reinterpret_cast<v4f*>(zi_blk + off));
            }
        };

        BAR();                            // match loader/consumer prologue
        for (int n = 0; n < NB; ++n) {
            // OUT[n-1] was sealed at barrier n-1; drain it during round n.
            // ds_reads are consumed into store-data regs before BAR (compiler
            // tracks these builtin stores), so the buffer is safe next round.
            if (n >= 1) drainbody(n - 1);
            SCHEDB();
            BAR();
        }
        drainbody(NB - 1);                // sealed at final barrier
    }
}

extern "C" void kernel_launch(void* const* d_in, const int* in_sizes, int n_in,
                              void* d_out, int out_size, void* d_ws, size_t ws_size,
                              hipStream_t stream) {
    const float* Xr = (const float*)d_in[0];
    const float* Xi = (const float*)d_in[1];
    const float* om = (const float*)d_in[2];
    float* zr = (float*)d_out;
    float* zi = zr + (size_t)B * T * D;   // tuple output 2, flat-concatenated

    hopf_scan<<<dim3(B * D / NDB), dim3(192), 0, stream>>>(Xr, Xi, om, zr, zi);
}

// Round 20
// 43.299 us; speedup vs baseline: 1.0440x; 1.0440x over previous
//
#include <hip/hip_runtime.h>
#include <hip/hip_bf16.h>

// Hopf oscillator scan: B=32, T=1000, D=512.
// THREE-wave specialization (R15 base, 44.0us best). R19 = R17/R18
// experiment, signature fix #2: this clang's raw_buffer_store_b128 takes an
// opaque __amdgpu_buffer_rsrc_t built by __builtin_amdgcn_make_buffer_rsrc
// (not a hand-packed v4i SRD). aux=18: NT(bit1)|SC1(bit4).
// Hypothesis: output writes allocating in the 256MB L3 evict half the
// 131MB inputs every dispatch (FETCH_SIZE=64MB). sc1/nt stores that skip
// L3 allocation leave inputs resident -> FETCH ~0, HBM side = writes only.
//   wave 0 (consumer): reg-burst IN reads, 40-step recurrence (phi in
//     revolutions, raw v_sin/v_cos), OUT write burst, lgkm seal.
//   wave 1 (loader): global_load_lds dwordx4, 3-deep ring, 2 bodies ahead,
//     hand-counted vmcnt (loads-only queue: steady vmcnt(20)).
//   wave 2 (drainer): OUT[n-1] -> buffer-store sc1-nt, off critical path.

#define B 32
#define T 1000
#define D 512
#define DTc 0.001f
#define K_IN 0.005f               // INPUT_SCALER * DT
#define KREV 7.95774715e-4f       // INPUT_SCALER * DT / (2*pi)
#define U 40                      // steps per body
#define NB (T / U)                // 25 bodies
#define NOPS (U / 4)              // 10 glds/drain ops per array per body
#define RING 3                    // IN ring depth

typedef float v4f __attribute__((ext_vector_type(4)));
typedef unsigned int v4u __attribute__((ext_vector_type(4)));
typedef const __attribute__((address_space(1))) float gfloat;
typedef __attribute__((address_space(3))) float lfloat;

#define SCHEDB() __builtin_amdgcn_sched_barrier(0)
#define BAR()    __builtin_amdgcn_s_barrier()
// s_waitcnt simm16 (gfx9): [3:0]=vmcnt lo, [15:14]=vmcnt hi, [6:4]=expcnt, [11:8]=lgkmcnt
#define W_LGKM0  0xC07F   // lgkmcnt(0) only
#define W_VM0    0x0F70   // vmcnt(0)  only
#define W_VM20   0x4F74   // vmcnt(20) only

// gfx94x/95x CPol for buffer ops: bit0=SC0, bit1=NT, bit4=SC1
#define AUX_NT_SC1 18

__global__ __launch_bounds__(192, 1) void hopf_scan(
    const float* __restrict__ Xr, const float* __restrict__ Xi,
    const float* __restrict__ om,
    float* __restrict__ zr, float* __restrict__ zi) {
    const int tid = threadIdx.x;
    const int bb = blockIdx.x;            // 0..255
    const int b = bb >> 3;
    const int dblk = (bb & 7) << 6;       // 64-d block
    const size_t blkoff = (size_t)b * (T * D) + dblk;

    __shared__ __align__(16) float INr[RING][U][64];   // 3-deep input ring
    __shared__ __align__(16) float INi[RING][U][64];
    __shared__ __align__(16) float OUTr[2][U][64];     // double-buffered out
    __shared__ __align__(16) float OUTi[2][U][64];

    if (tid < 64) {
        // ---------------- wave 0: consumer (LDS + VALU only) ----------------
        const int i = tid;
        // rev/step: f_Hz * dt = (om*10 + 0.1) * dt
        const float od = __builtin_fmaf(om[dblk + i], 10.0f, 0.1f) * DTc;
        float r = 1.0f, phi = 0.0f, c = 1.0f, s = 0.0f;  // phi in revolutions

        BAR();                            // body 0 staged by loader
        int ib = 0;                       // ring slot of body n (mod 3)
        for (int n = 0; n < NB; ++n) {
            const int ob = n & 1;

            float xr[U], xi[U];
#pragma unroll
            for (int t = 0; t < U; ++t) {   // reg-burst: latency pipelines
                xr[t] = INr[ib][t][i];
                xi[t] = INi[ib][t][i];
            }
            SCHEDB();

            float our[U], oui[U];
#pragma unroll
            for (int t = 0; t < U; ++t) {
                const float omr2 = __builtin_fmaf(-r, r, 1.0f);   // 1 - r^2
                r = __builtin_fmaf(omr2 * r, DTc, r);             // + cubic*dt
                r = __builtin_fmaf(K_IN * xr[t], c, r);           // + K*xr*cos
                phi = __builtin_fmaf(-(KREV * xi[t]), s, phi + od);
                s = __builtin_amdgcn_sinf(phi);   // v_sin: input in revs
                c = __builtin_amdgcn_cosf(phi);
                our[t] = r * c;
                oui[t] = r * s;
            }
            SCHEDB();
#pragma unroll
            for (int t = 0; t < U; ++t) {
                OUTr[ob][t][i] = our[t];
                OUTi[ob][t][i] = oui[t];
            }
            __builtin_amdgcn_s_waitcnt(W_LGKM0);  // OUT complete before BAR
            SCHEDB();
            BAR();
            ib = (ib == RING - 1) ? 0 : ib + 1;
        }
    } else if (tid < 128) {
        // ---------------- wave 1: loader (global->LDS only) -----------------
        const int i = tid - 64;
        const int ts = i >> 4;            // sub-step 0..3 of a glds op
        const int dq = (i & 15) << 2;     // d quad
        const float* __restrict__ xr_blk = Xr + blkoff;
        const float* __restrict__ xi_blk = Xi + blkoff;

        auto issueglds = [&](int body, int buf) {
#pragma unroll
            for (int k = 0; k < NOPS; ++k) {
                const size_t off = (size_t)(body * U + 4 * k + ts) * D + dq;
                __builtin_amdgcn_global_load_lds((gfloat*)(xr_blk + off),
                                                 (lfloat*)&INr[buf][4 * k][0], 16, 0, 0);
                __builtin_amdgcn_global_load_lds((gfloat*)(xi_blk + off),
                                                 (lfloat*)&INi[buf][4 * k][0], 16, 0, 0);
            }
        };

        // prologue: bodies 0,1 in flight; body 0 landed when <=20 newer remain
        issueglds(0, 0);
        issueglds(1, 1);
        __builtin_amdgcn_s_waitcnt(W_VM20);
        SCHEDB();
        BAR();

        int bufn = 2;                     // ring slot for body n+2 (mod 3)
        for (int n = 0; n < NB; ++n) {
            if (n + 2 < NB) issueglds(n + 2, bufn);
            SCHEDB();
            if (n + 1 < NB) {
                // loads-only queue: ops newer than body n+1's are body n+2's
                // 20 (if issued).
                if (n + 2 < NB) __builtin_amdgcn_s_waitcnt(W_VM20);
                else            __builtin_amdgcn_s_waitcnt(W_VM0);
            }
            SCHEDB();
            BAR();
            bufn = (bufn == RING - 1) ? 0 : bufn + 1;
        }
    } else {
        // ---------------- wave 2: drainer (LDS->global only) ----------------
        const int i = tid - 128;
        const int ts = i >> 4;
        const int dq = (i & 15) << 2;
        // opaque buffer resources: stride=0, num_records=disabled, raw flags
        const __amdgpu_buffer_rsrc_t srd_r =
            __builtin_amdgcn_make_buffer_rsrc((void*)zr, (short)0,
                                              (int)0xffffffff, 0x00020000);
        const __amdgpu_buffer_rsrc_t srd_i =
            __builtin_amdgcn_make_buffer_rsrc((void*)zi, (short)0,
                                              (int)0xffffffff, 0x00020000);
        const unsigned boff = (unsigned)blkoff;   // block base, elements

        auto drainbody = [&](int body) {
            const int ob = body & 1;
#pragma unroll
            for (int k = 0; k < NOPS; ++k) {
                const unsigned off = (boff + (unsigned)((body * U + 4 * k + ts) * D + dq)) * 4u;
                const v4u vr = *reinterpret_cast<const v4u*>(&OUTr[ob][4 * k + ts][dq]);
                const v4u vi = *reinterpret_cast<const v4u*>(&OUTi[ob][4 * k + ts][dq]);
                // sc1|nt cache policy: don't allocate the output stream in
                // L3 so the 131MB inputs stay resident across graph replays.
                __builtin_amdgcn_raw_buffer_store_b128(vr, srd_r, off, 0, AUX_NT_SC1);
                __builtin_amdgcn_raw_buffer_store_b128(vi, srd_i, off, 0, AUX_NT_SC1);
            }
        };

        BAR();                            // match loader/consumer prologue
        for (int n = 0; n < NB; ++n) {
            // OUT[n-1] was sealed at barrier n-1; drain it during round n.
            // Intrinsic stores are hazard-tracked: ds_read results get lgkm
            // waits, store-data regs are protected before reuse.
            if (n >= 1) drainbody(n - 1);
            SCHEDB();
            BAR();
        }
        drainbody(NB - 1);                // sealed at final barrier
    }
}

extern "C" void kernel_launch(void* const* d_in, const int* in_sizes, int n_in,
                              void* d_out, int out_size, void* d_ws, size_t ws_size,
                              hipStream_t stream) {
    const float* Xr = (const float*)d_in[0];
    const float* Xi = (const float*)d_in[1];
    const float* om = (const float*)d_in[2];
    float* zr = (float*)d_out;
    float* zi = zr + (size_t)B * T * D;   // tuple output 2, flat-concatenated

    hopf_scan<<<dim3(B * D / 64), dim3(192), 0, stream>>>(Xr, Xi, om, zr, zi);
}